// Round 9
// baseline (523.993 us; speedup 1.0000x reference)
//
#include <hip/hip_runtime.h>

typedef __attribute__((ext_vector_type(8))) short short8;
typedef __attribute__((ext_vector_type(4))) float f32x4;

#define SCHUNK 2048   // elements per scan block (256 threads x 8)
#define MAXN   20480  // LDS histogram capacity (n = 20000)
#define NSLICE 8      // feature slices (32 floats each) -> XCD pinning
#define NPB    40     // nodes per pull block chunk (10 contiguous per wave)

// ---------------------------------------------------------------- bf16 split helpers
__device__ inline unsigned short f2bf(float v) {
    unsigned u = __float_as_uint(v);
    u += 0x7FFFu + ((u >> 16) & 1u);   // RNE
    return (unsigned short)(u >> 16);
}
__device__ inline float bf2f(unsigned short h) {
    return __uint_as_float((unsigned)h << 16);
}

// ---------------------------------------------------------------- bias sums
__global__ void bias_sum_kernel(const float* __restrict__ b1s, const float* __restrict__ b1u,
                                const float* __restrict__ b2s, const float* __restrict__ b2u,
                                float* __restrict__ bsum1, float* __restrict__ bsum2) {
    int i = threadIdx.x;
    bsum1[i] = b1s[i] + b1u[i];
    bsum2[i] = b2s[i] + b2u[i];
}

// ---------------------------------------------------------------- W prep: fragment-packed bf16 split
// Bpk layout: [ntile(16)][kstep(16)][plane(2)][lane(64)][8] shorts.
__global__ void wprep_kernel(const float* __restrict__ W1s, const float* __restrict__ W1u,
                             const float* __restrict__ W2s, const float* __restrict__ W2u,
                             unsigned short* __restrict__ Bpk1, unsigned short* __restrict__ Bpk2) {
    int k = blockIdx.x;        // 0..511
    int nn = threadIdx.x;      // 0..255
    int layer = blockIdx.y;
    const float* Ws = layer ? W2s : W1s;
    const float* Wu = layer ? W2u : W1u;
    float w = (k < 256) ? Ws[k * 256 + nn] : Wu[(k - 256) * 256 + nn];
    unsigned short hi = f2bf(w);
    unsigned short lo = f2bf(w - bf2f(hi));
    unsigned short* B = layer ? Bpk2 : Bpk1;
    size_t frag = ((size_t)(nn >> 4) * 16 + (k >> 5)) * 2;           // *2 planes
    size_t addr = frag * 512 + ((nn & 15) + ((k >> 3) & 3) * 16) * 8 + (k & 7);
    B[addr] = hi;          // plane 0
    B[addr + 512] = lo;    // plane 1
}

// ---------------------------------------------------------------- phase H: per-block packed histograms
__global__ __launch_bounds__(256) void hist_kernel(
    const int* __restrict__ sS, const int* __restrict__ dS,
    const int* __restrict__ sU, const int* __restrict__ dU,
    int Es, int Eu, int n, int nblk, unsigned int* __restrict__ histG) {
    __shared__ unsigned int h[MAXN];
    const int rel = blockIdx.y;
    const int* src = rel ? sU : sS;
    const int* dst = rel ? dU : dS;
    int E = rel ? Eu : Es;
    int b = blockIdx.x;
    int chunk = (E + nblk - 1) / nblk;
    int beg = b * chunk;
    int end = min(E, beg + chunk);
    for (int i = threadIdx.x; i < n; i += 256) h[i] = 0u;
    __syncthreads();
    for (int i = beg + threadIdx.x; i < end; i += 256) {
        atomicAdd(&h[src[i]], 1u);
        atomicAdd(&h[dst[i]], 0x10000u);
    }
    __syncthreads();
    unsigned int* out = histG + ((size_t)rel * nblk + b) * n;
    for (int i = threadIdx.x; i < n; i += 256) out[i] = h[i];
}

// ---------------------------------------------------------------- phase B1: totals -> scales + deg_in
__global__ void totals_kernel(const unsigned int* __restrict__ histG, int n, int nblk,
                              float* __restrict__ sOutS, float* __restrict__ sInS,
                              float* __restrict__ sOutU, float* __restrict__ sInU,
                              int* __restrict__ degInS, int* __restrict__ degInU) {
    const int rel = blockIdx.y;
    int i = blockIdx.x * 256 + threadIdx.x;
    if (i >= n) return;
    const unsigned int* hg = histG + (size_t)rel * nblk * n;
    unsigned int lo = 0, hi = 0;
    for (int b = 0; b < nblk; ++b) {
        unsigned int v = hg[(size_t)b * n + i];
        lo += v & 0xFFFFu;
        hi += v >> 16;
    }
    float so = rsqrtf((float)(lo > 1u ? lo : 1u));
    float si = rsqrtf((float)(hi > 1u ? hi : 1u));
    if (rel) { sOutU[i] = so; sInU[i] = si; degInU[i] = (int)hi; }
    else     { sOutS[i] = so; sInS[i] = si; degInS[i] = (int)hi; }
}

// ---------------------------------------------------------------- scan phase 1
__global__ __launch_bounds__(256) void scan_part_kernel(const int* __restrict__ degA,
                                                        const int* __restrict__ degB,
                                                        int n, int NB, int* __restrict__ bsum) {
    const int rel = blockIdx.y;
    const int* deg = rel ? degB : degA;
    int t = threadIdx.x;
    int base = blockIdx.x * SCHUNK + t * 8;
    int s = 0;
    if (base + 8 <= n) {
        int4 a = *(const int4*)(deg + base);
        int4 b = *(const int4*)(deg + base + 4);
        s = a.x + a.y + a.z + a.w + b.x + b.y + b.z + b.w;
    } else {
        for (int i = 0; i < 8; ++i)
            if (base + i < n) s += deg[base + i];
    }
    __shared__ int sm[256];
    sm[t] = s;
    __syncthreads();
    for (int off = 128; off > 0; off >>= 1) {
        if (t < off) sm[t] += sm[t + off];
        __syncthreads();
    }
    if (t == 0) bsum[rel * NB + blockIdx.x] = sm[0];
}

// ---------------------------------------------------------------- scan phase 2
__global__ void scan_mid_kernel(int* __restrict__ bsum, int NB,
                                int* __restrict__ rpA, int* __restrict__ rpB, int n) {
    int t = threadIdx.x;
    if (t >= 2) return;
    int* bs = bsum + t * NB;
    int run = 0;
    for (int i = 0; i < NB; ++i) {
        int v = bs[i];
        bs[i] = run;
        run += v;
    }
    int* rp = t ? rpB : rpA;
    rp[n] = run;
}

// ---------------------------------------------------------------- scan phase 3
__global__ __launch_bounds__(256) void scan_final_kernel(const int* __restrict__ degA,
                                                         const int* __restrict__ degB,
                                                         const int* __restrict__ bsum,
                                                         int n, int NB,
                                                         int* __restrict__ rpA,
                                                         int* __restrict__ rpB) {
    const int rel = blockIdx.y;
    const int* deg = rel ? degB : degA;
    int* rp = rel ? rpB : rpA;
    int t = threadIdx.x;
    int base = blockIdx.x * SCHUNK + t * 8;
    int v[8];
    if (base + 8 <= n) {
        int4 a = *(const int4*)(deg + base);
        int4 b = *(const int4*)(deg + base + 4);
        v[0] = a.x; v[1] = a.y; v[2] = a.z; v[3] = a.w;
        v[4] = b.x; v[5] = b.y; v[6] = b.z; v[7] = b.w;
    } else {
        for (int i = 0; i < 8; ++i) v[i] = (base + i < n) ? deg[base + i] : 0;
    }
    int s = 0;
    #pragma unroll
    for (int i = 0; i < 8; ++i) s += v[i];
    __shared__ int sm[256];
    sm[t] = s;
    __syncthreads();
    #pragma unroll
    for (int off = 1; off < 256; off <<= 1) {
        int y = (t >= off) ? sm[t - off] : 0;
        __syncthreads();
        sm[t] += y;
        __syncthreads();
    }
    int run = bsum[rel * NB + blockIdx.x] + sm[t] - s;
    #pragma unroll
    for (int i = 0; i < 8; ++i) {
        if (base + i < n) rp[base + i] = run;
        run += v[i];
    }
}

// ---------------------------------------------------------------- phase B2: per-block scatter offsets
__global__ void offsets_kernel(const unsigned int* __restrict__ histG,
                               const int* __restrict__ rpS, const int* __restrict__ rpU,
                               int n, int nblk, int* __restrict__ offsG) {
    const int rel = blockIdx.y;
    int i = blockIdx.x * 256 + threadIdx.x;
    if (i >= n) return;
    const unsigned int* hg = histG + (size_t)rel * nblk * n;
    int* og = offsG + (size_t)rel * nblk * n;
    int run = (rel ? rpU : rpS)[i];
    for (int b = 0; b < nblk; ++b) {
        og[(size_t)b * n + i] = run;
        run += (int)(hg[(size_t)b * n + i] >> 16);
    }
}

// ---------------------------------------------------------------- phase C: CSR scatter, packed (u, w)
__global__ __launch_bounds__(256) void csr_scatter_kernel(
    const int* __restrict__ sS, const int* __restrict__ dS,
    const int* __restrict__ sU, const int* __restrict__ dU,
    int Es, int Eu, int n, int nblk, const int* __restrict__ offsG,
    const float* __restrict__ sOutS, const float* __restrict__ sOutU,
    int2* __restrict__ csrPS, int2* __restrict__ csrPU) {
    __shared__ int off[MAXN];
    const int rel = blockIdx.y;
    const int* src = rel ? sU : sS;
    const int* dst = rel ? dU : dS;
    const float* so = rel ? sOutU : sOutS;
    int2* csrP = rel ? csrPU : csrPS;
    int E = rel ? Eu : Es;
    int b = blockIdx.x;
    int chunk = (E + nblk - 1) / nblk;  // MUST match hist_kernel
    int beg = b * chunk;
    int end = min(E, beg + chunk);
    const int* og = offsG + ((size_t)rel * nblk + b) * n;
    for (int i = threadIdx.x; i < n; i += 256) off[i] = og[i];
    __syncthreads();
    for (int i = beg + threadIdx.x; i < end; i += 256) {
        int s = src[i];
        int pos = atomicAdd(&off[dst[i]], 1);
        csrP[pos] = make_int2(s, __float_as_int(so[s]));
    }
}

// ---------------------------------------------------------------- sliced pull aggregation, pair-interleaved
// block = (chunk, rel, slice); slice = blockIdx.x & 7 pins slice -> XCD (2.56 MB/XCD L2).
// Each wave owns 10 contiguous nodes, processed in PAIRS: both nodes' 64-edge
// batches in registers, dual-unrolled consume issues 8 independent 16B gathers
// before the FMAs (2x the in-flight count of the single-node version).
// Lanes >= cnt hold w=0, so the dual loop needs no validity branches.
#define DUAL4(J0) {                                                                   \
    int i0 = (J0) * 8 + sub;                                                          \
    int u0 = __shfl(myuA, i0),      u1 = __shfl(myuA, i0 + 8);                        \
    int u2 = __shfl(myuA, i0 + 16), u3 = __shfl(myuA, i0 + 24);                       \
    int v0 = __shfl(myuB, i0),      v1 = __shfl(myuB, i0 + 8);                        \
    int v2 = __shfl(myuB, i0 + 16), v3 = __shfl(myuB, i0 + 24);                       \
    float p0 = __shfl(mywA, i0),      p1 = __shfl(mywA, i0 + 8);                      \
    float p2 = __shfl(mywA, i0 + 16), p3 = __shfl(mywA, i0 + 24);                     \
    float q0 = __shfl(mywB, i0),      q1 = __shfl(mywB, i0 + 8);                      \
    float q2 = __shfl(mywB, i0 + 16), q3 = __shfl(mywB, i0 + 24);                     \
    float4 a0 = xin[(size_t)u0 * 64 + fbase], a1 = xin[(size_t)u1 * 64 + fbase];      \
    float4 a2 = xin[(size_t)u2 * 64 + fbase], a3 = xin[(size_t)u3 * 64 + fbase];      \
    float4 b0 = xin[(size_t)v0 * 64 + fbase], b1 = xin[(size_t)v1 * 64 + fbase];      \
    float4 b2 = xin[(size_t)v2 * 64 + fbase], b3 = xin[(size_t)v3 * 64 + fbase];      \
    axA += p0 * a0.x + p1 * a1.x + p2 * a2.x + p3 * a3.x;                             \
    ayA += p0 * a0.y + p1 * a1.y + p2 * a2.y + p3 * a3.y;                             \
    azA += p0 * a0.z + p1 * a1.z + p2 * a2.z + p3 * a3.z;                             \
    awA += p0 * a0.w + p1 * a1.w + p2 * a2.w + p3 * a3.w;                             \
    axB += q0 * b0.x + q1 * b1.x + q2 * b2.x + q3 * b3.x;                             \
    ayB += q0 * b0.y + q1 * b1.y + q2 * b2.y + q3 * b3.y;                             \
    azB += q0 * b0.z + q1 * b1.z + q2 * b2.z + q3 * b3.z;                             \
    awB += q0 * b0.w + q1 * b1.w + q2 * b2.w + q3 * b3.w;                             \
}

__global__ __launch_bounds__(256) void pull_slice_kernel(
    const float4* __restrict__ xin,      // [n][64] float4
    const int2* __restrict__ csrPS, const int2* __restrict__ csrPU,
    const int* __restrict__ rpS, const int* __restrict__ rpU,
    const float* __restrict__ sinS, const float* __restrict__ sinU,
    unsigned short* __restrict__ aggPk, int n) {
    int bid = blockIdx.x;
    int slice = bid & (NSLICE - 1);
    int rest = bid >> 3;
    int rel = rest & 1;
    int chunk = rest >> 1;
    const int2* csrP = rel ? csrPU : csrPS;
    const int* rp = rel ? rpU : rpS;
    const float* sinv = rel ? sinU : sinS;

    int wave = threadIdx.x >> 6;
    int lane = threadIdx.x & 63;
    int sub = lane >> 3;          // 0..7 edge slot
    int sl = lane & 7;            // float4 index within slice
    int fbase = slice * 8 + sl;
    int kstepg = rel * 8 + slice;

    int start = chunk * NPB;
    int lim = min(n, start + NPB);
    int base = start + wave * (NPB / 4);
    int limW = min(lim, base + NPB / 4);

    for (int pn = base; pn < limW; pn += 2) {
        int nA = pn;
        int nB = pn + 1;
        bool dual = nB < limW;
        int begA = rp[nA], endA = rp[nA + 1];
        int begB = 0, endB = 0;
        if (dual) { begB = rp[nB]; endB = rp[nB + 1]; }
        float axA = 0.f, ayA = 0.f, azA = 0.f, awA = 0.f;
        float axB = 0.f, ayB = 0.f, azB = 0.f, awB = 0.f;
        int ebA = begA, ebB = begB;
        while (ebA < endA || ebB < endB) {
            int remA = endA - ebA;
            int cntA = remA < 0 ? 0 : (remA > 64 ? 64 : remA);
            int remB = endB - ebB;
            int cntB = remB < 0 ? 0 : (remB > 64 ? 64 : remB);
            int myuA = 0, myuB = 0;
            float mywA = 0.f, mywB = 0.f;
            if (lane < cntA) {
                int2 p = csrP[ebA + lane];
                myuA = p.x; mywA = __int_as_float(p.y);
            }
            if (lane < cntB) {
                int2 p = csrP[ebB + lane];
                myuB = p.x; mywB = __int_as_float(p.y);
            }
            DUAL4(0);
            int cmax = cntA > cntB ? cntA : cntB;
            if (cmax > 32) DUAL4(4);
            ebA += cntA;
            ebB += cntB;
        }
        // reduce across the 8 subgroups (lane bits 3,4,5) - two independent trees
        axA += __shfl_xor(axA, 8); ayA += __shfl_xor(ayA, 8);
        azA += __shfl_xor(azA, 8); awA += __shfl_xor(awA, 8);
        axB += __shfl_xor(axB, 8); ayB += __shfl_xor(ayB, 8);
        azB += __shfl_xor(azB, 8); awB += __shfl_xor(awB, 8);
        axA += __shfl_xor(axA, 16); ayA += __shfl_xor(ayA, 16);
        azA += __shfl_xor(azA, 16); awA += __shfl_xor(awA, 16);
        axB += __shfl_xor(axB, 16); ayB += __shfl_xor(ayB, 16);
        azB += __shfl_xor(azB, 16); awB += __shfl_xor(awB, 16);
        axA += __shfl_xor(axA, 32); ayA += __shfl_xor(ayA, 32);
        azA += __shfl_xor(azA, 32); awA += __shfl_xor(awA, 32);
        axB += __shfl_xor(axB, 32); ayB += __shfl_xor(ayB, 32);
        azB += __shfl_xor(azB, 32); awB += __shfl_xor(awB, 32);
        if (sub == 0) {
            {
                float si = sinv[nA];
                float vx = si * axA, vy = si * ayA, vz = si * azA, vw = si * awA;
                ushort4 hi4 = make_ushort4(f2bf(vx), f2bf(vy), f2bf(vz), f2bf(vw));
                ushort4 lo4 = make_ushort4(f2bf(vx - bf2f(hi4.x)), f2bf(vy - bf2f(hi4.y)),
                                           f2bf(vz - bf2f(hi4.z)), f2bf(vw - bf2f(hi4.w)));
                size_t frag = ((size_t)(nA >> 4) * 16 + kstepg) * 2;
                size_t addr = frag * 512 + ((nA & 15) + (sl >> 1) * 16) * 8 + (sl & 1) * 4;
                *(ushort4*)&aggPk[addr] = hi4;
                *(ushort4*)&aggPk[addr + 512] = lo4;
            }
            if (dual) {
                float si = sinv[nB];
                float vx = si * axB, vy = si * ayB, vz = si * azB, vw = si * awB;
                ushort4 hi4 = make_ushort4(f2bf(vx), f2bf(vy), f2bf(vz), f2bf(vw));
                ushort4 lo4 = make_ushort4(f2bf(vx - bf2f(hi4.x)), f2bf(vy - bf2f(hi4.y)),
                                           f2bf(vz - bf2f(hi4.z)), f2bf(vw - bf2f(hi4.w)));
                size_t frag = ((size_t)(nB >> 4) * 16 + kstepg) * 2;
                size_t addr = frag * 512 + ((nB & 15) + (sl >> 1) * 16) * 8 + (sl & 1) * 4;
                *(ushort4*)&aggPk[addr] = hi4;
                *(ushort4*)&aggPk[addr + 512] = lo4;
            }
        }
    }
}

// ---------------------------------------------------------------- split-bf16 MFMA GEMM, packed frags
// C[M x 256] = (Ahi+Alo)[M x 512] @ W (+bias)(+relu), hi*hi + lo*hi + hi*lo.
// BM=80 (5 mtiles), 512 threads / 8 waves, wave = 2 ntiles (32 cols).
template <int RELU>
__global__ __launch_bounds__(512) void gemm_mfma_kernel(
    const short8* __restrict__ Apk, const short8* __restrict__ Bpk,
    const float* __restrict__ bias, float* __restrict__ C, int M) {
    int lane = threadIdx.x & 63;
    int wv = threadIdx.x >> 6;     // 0..7
    int mt0 = blockIdx.x * 5;
    int m0 = blockIdx.x * 80;
    if (m0 >= M) return;
    int nt0 = wv * 2;
    int col0 = wv * 32;
    int frow = lane & 15;

    f32x4 acc[5][2];
    #pragma unroll
    for (int fr = 0; fr < 5; ++fr)
        #pragma unroll
        for (int fc = 0; fc < 2; ++fc)
            acc[fr][fc] = (f32x4){0.f, 0.f, 0.f, 0.f};

    #pragma unroll
    for (int ks = 0; ks < 16; ++ks) {
        short8 ah[5], al[5], bh[2], bl[2];
        #pragma unroll
        for (int fr = 0; fr < 5; ++fr) {
            size_t fa = ((size_t)(mt0 + fr) * 16 + ks) * 128 + lane;
            ah[fr] = Apk[fa];
            al[fr] = Apk[fa + 64];
        }
        #pragma unroll
        for (int fc = 0; fc < 2; ++fc) {
            size_t fb = ((size_t)(nt0 + fc) * 16 + ks) * 128 + lane;
            bh[fc] = Bpk[fb];
            bl[fc] = Bpk[fb + 64];
        }
        #pragma unroll
        for (int fr = 0; fr < 5; ++fr)
            #pragma unroll
            for (int fc = 0; fc < 2; ++fc) {
                acc[fr][fc] = __builtin_amdgcn_mfma_f32_16x16x32_bf16(ah[fr], bh[fc], acc[fr][fc], 0, 0, 0);
                acc[fr][fc] = __builtin_amdgcn_mfma_f32_16x16x32_bf16(al[fr], bh[fc], acc[fr][fc], 0, 0, 0);
                acc[fr][fc] = __builtin_amdgcn_mfma_f32_16x16x32_bf16(ah[fr], bl[fc], acc[fr][fc], 0, 0, 0);
            }
    }

    #pragma unroll
    for (int fr = 0; fr < 5; ++fr)
        #pragma unroll
        for (int fc = 0; fc < 2; ++fc) {
            int c = col0 + fc * 16 + frow;
            float bc = bias[c];
            int rb = m0 + fr * 16 + (lane >> 4) * 4;
            #pragma unroll
            for (int j = 0; j < 4; ++j) {
                int r = rb + j;
                if (r < M) {
                    float v = acc[fr][fc][j] + bc;
                    if (RELU) v = fmaxf(v, 0.f);
                    C[(size_t)r * 256 + c] = v;
                }
            }
        }
}

// ---------------------------------------------------------------- launch
extern "C" void kernel_launch(void* const* d_in, const int* in_sizes, int n_in,
                              void* d_out, int out_size, void* d_ws, size_t ws_size,
                              hipStream_t stream) {
    const float* x   = (const float*)d_in[0];
    const int* sS    = (const int*)d_in[1];
    const int* dS    = (const int*)d_in[2];
    const int* sU    = (const int*)d_in[3];
    const int* dU    = (const int*)d_in[4];
    const float* W1s = (const float*)d_in[5];
    const float* b1s = (const float*)d_in[6];
    const float* W1u = (const float*)d_in[7];
    const float* b1u = (const float*)d_in[8];
    const float* W2s = (const float*)d_in[9];
    const float* b2s = (const float*)d_in[10];
    const float* W2u = (const float*)d_in[11];
    const float* b2u = (const float*)d_in[12];
    float* out = (float*)d_out;

    const int n  = in_sizes[0] / 256;
    const int Es = in_sizes[1];
    const int Eu = in_sizes[3];
    const int NB = (n + SCHUNK - 1) / SCHUNK;
    const int gemmGrid = (n + 79) / 80;
    const size_t AGG_BYTES = (size_t)((n + 15) / 16 + 16) * 16 * 2 * 512 * 2;
    const size_t BPK_BYTES = (size_t)16 * 16 * 2 * 512 * 2;

    auto plan = [&](int nb) -> size_t {
        size_t t = 0;
        auto add = [&](size_t b) { t = (t + 255) & ~(size_t)255; t += b; };
        add((size_t)2 * nb * n * 4);            // histG
        add((size_t)2 * nb * n * 4);            // offsG
        add((size_t)(n + 1) * 4); add((size_t)(n + 1) * 4);
        add((size_t)n * 4); add((size_t)n * 4); add((size_t)n * 4); add((size_t)n * 4);
        add((size_t)n * 4); add((size_t)n * 4); // degIn
        add(256 * 4); add(256 * 4);
        add((size_t)2 * NB * 4);
        add((size_t)Es * 8); add((size_t)Eu * 8);
        add(2 * BPK_BYTES);
        add(AGG_BYTES);
        add((size_t)n * 256 * 4);               // h
        return t;
    };
    const int nblk = (plan(128) <= ws_size) ? 128 : 32;

    char* ws = (char*)d_ws;
    size_t off = 0;
    auto alloc = [&](size_t bytes) -> void* {
        off = (off + 255) & ~(size_t)255;
        void* p = ws + off;
        off += bytes;
        return p;
    };

    unsigned int* histG = (unsigned int*)alloc((size_t)2 * nblk * n * 4);
    int* offsG   = (int*)alloc((size_t)2 * nblk * n * 4);
    int* rpS     = (int*)alloc((size_t)(n + 1) * 4);
    int* rpU     = (int*)alloc((size_t)(n + 1) * 4);
    float* sOutS = (float*)alloc((size_t)n * 4);
    float* sInS  = (float*)alloc((size_t)n * 4);
    float* sOutU = (float*)alloc((size_t)n * 4);
    float* sInU  = (float*)alloc((size_t)n * 4);
    int* degInS  = (int*)alloc((size_t)n * 4);
    int* degInU  = (int*)alloc((size_t)n * 4);
    float* bsum1 = (float*)alloc(256 * 4);
    float* bsum2 = (float*)alloc(256 * 4);
    int* bsumBlk = (int*)alloc((size_t)2 * NB * 4);
    int2* csrPS  = (int2*)alloc((size_t)Es * 8);
    int2* csrPU  = (int2*)alloc((size_t)Eu * 8);
    unsigned short* Bpk1 = (unsigned short*)alloc(2 * BPK_BYTES);
    unsigned short* Bpk2 = Bpk1 + BPK_BYTES / 2;
    unsigned short* aggPk = (unsigned short*)alloc(AGG_BYTES);
    float* h     = (float*)alloc((size_t)n * 256 * 4);

    // ---- preprocessing (no global atomics)
    bias_sum_kernel<<<1, 256, 0, stream>>>(b1s, b1u, b2s, b2u, bsum1, bsum2);
    wprep_kernel<<<dim3(512, 2), 256, 0, stream>>>(W1s, W1u, W2s, W2u, Bpk1, Bpk2);
    dim3 hg(nblk, 2);
    hist_kernel<<<hg, 256, 0, stream>>>(sS, dS, sU, dU, Es, Eu, n, nblk, histG);
    dim3 tg((n + 255) / 256, 2);
    totals_kernel<<<tg, 256, 0, stream>>>(histG, n, nblk, sOutS, sInS, sOutU, sInU,
                                          degInS, degInU);
    dim3 sg(NB, 2);
    scan_part_kernel<<<sg, 256, 0, stream>>>(degInS, degInU, n, NB, bsumBlk);
    scan_mid_kernel<<<1, 64, 0, stream>>>(bsumBlk, NB, rpS, rpU, n);
    scan_final_kernel<<<sg, 256, 0, stream>>>(degInS, degInU, bsumBlk, n, NB, rpS, rpU);
    offsets_kernel<<<tg, 256, 0, stream>>>(histG, rpS, rpU, n, nblk, offsG);
    csr_scatter_kernel<<<hg, 256, 0, stream>>>(sS, dS, sU, dU, Es, Eu, n, nblk, offsG,
                                               sOutS, sOutU, csrPS, csrPU);

    // ---- layers
    int chunks = (n + NPB - 1) / NPB;
    int pullGrid = NSLICE * 2 * chunks;
    const float4* x4 = (const float4*)x;
    const float4* h4 = (const float4*)h;
    const short8* A8 = (const short8*)aggPk;
    const short8* B81 = (const short8*)Bpk1;
    const short8* B82 = (const short8*)Bpk2;

    pull_slice_kernel<<<pullGrid, 256, 0, stream>>>(x4, csrPS, csrPU, rpS, rpU,
                                                    sInS, sInU, aggPk, n);
    gemm_mfma_kernel<1><<<gemmGrid, 512, 0, stream>>>(A8, B81, bsum1, h, n);
    pull_slice_kernel<<<pullGrid, 256, 0, stream>>>(h4, csrPS, csrPU, rpS, rpU,
                                                    sInS, sInU, aggPk, n);
    gemm_mfma_kernel<0><<<gemmGrid, 512, 0, stream>>>(A8, B82, bsum2, out, n);
}

// Round 10
// 456.636 us; speedup vs baseline: 1.1475x; 1.1475x over previous
//
#include <hip/hip_runtime.h>

typedef __attribute__((ext_vector_type(8))) short short8;
typedef __attribute__((ext_vector_type(4))) float f32x4;

#define SCHUNK 2048   // elements per scan block (256 threads x 8)
#define MAXN   20480  // LDS histogram capacity (n = 20000)
#define NSLICE 8      // feature slices (32 floats each) -> XCD pinning
#define NPB    40     // nodes per pull block chunk (10 per wave)

// ---------------------------------------------------------------- bf16 split helpers
__device__ inline unsigned short f2bf(float v) {
    unsigned u = __float_as_uint(v);
    u += 0x7FFFu + ((u >> 16) & 1u);   // RNE
    return (unsigned short)(u >> 16);
}
__device__ inline float bf2f(unsigned short h) {
    return __uint_as_float((unsigned)h << 16);
}

// ---------------------------------------------------------------- bias sums
__global__ void bias_sum_kernel(const float* __restrict__ b1s, const float* __restrict__ b1u,
                                const float* __restrict__ b2s, const float* __restrict__ b2u,
                                float* __restrict__ bsum1, float* __restrict__ bsum2) {
    int i = threadIdx.x;
    bsum1[i] = b1s[i] + b1u[i];
    bsum2[i] = b2s[i] + b2u[i];
}

// ---------------------------------------------------------------- W prep: fragment-packed bf16 split
// Bpk layout: [ntile(16)][kstep(16)][plane(2)][lane(64)][8] shorts.
__global__ void wprep_kernel(const float* __restrict__ W1s, const float* __restrict__ W1u,
                             const float* __restrict__ W2s, const float* __restrict__ W2u,
                             unsigned short* __restrict__ Bpk1, unsigned short* __restrict__ Bpk2) {
    int k = blockIdx.x;        // 0..511
    int nn = threadIdx.x;      // 0..255
    int layer = blockIdx.y;
    const float* Ws = layer ? W2s : W1s;
    const float* Wu = layer ? W2u : W1u;
    float w = (k < 256) ? Ws[k * 256 + nn] : Wu[(k - 256) * 256 + nn];
    unsigned short hi = f2bf(w);
    unsigned short lo = f2bf(w - bf2f(hi));
    unsigned short* B = layer ? Bpk2 : Bpk1;
    size_t frag = ((size_t)(nn >> 4) * 16 + (k >> 5)) * 2;           // *2 planes
    size_t addr = frag * 512 + ((nn & 15) + ((k >> 3) & 3) * 16) * 8 + (k & 7);
    B[addr] = hi;          // plane 0
    B[addr + 512] = lo;    // plane 1
}

// ---------------------------------------------------------------- phase H: per-block packed histograms
__global__ __launch_bounds__(256) void hist_kernel(
    const int* __restrict__ sS, const int* __restrict__ dS,
    const int* __restrict__ sU, const int* __restrict__ dU,
    int Es, int Eu, int n, int nblk, unsigned int* __restrict__ histG) {
    __shared__ unsigned int h[MAXN];
    const int rel = blockIdx.y;
    const int* src = rel ? sU : sS;
    const int* dst = rel ? dU : dS;
    int E = rel ? Eu : Es;
    int b = blockIdx.x;
    int chunk = (E + nblk - 1) / nblk;
    int beg = b * chunk;
    int end = min(E, beg + chunk);
    for (int i = threadIdx.x; i < n; i += 256) h[i] = 0u;
    __syncthreads();
    for (int i = beg + threadIdx.x; i < end; i += 256) {
        atomicAdd(&h[src[i]], 1u);
        atomicAdd(&h[dst[i]], 0x10000u);
    }
    __syncthreads();
    unsigned int* out = histG + ((size_t)rel * nblk + b) * n;
    for (int i = threadIdx.x; i < n; i += 256) out[i] = h[i];
}

// ---------------------------------------------------------------- phase B1: totals -> scales + deg_in
// Unrolled x8: 8 independent strided loads in flight (the naive loop was
// latency-serialized: ~600cy cross-XCD L2/L3 per load x 128 deep).
__global__ void totals_kernel(const unsigned int* __restrict__ histG, int n, int nblk,
                              float* __restrict__ sOutS, float* __restrict__ sInS,
                              float* __restrict__ sOutU, float* __restrict__ sInU,
                              int* __restrict__ degInS, int* __restrict__ degInU) {
    const int rel = blockIdx.y;
    int i = blockIdx.x * 256 + threadIdx.x;
    if (i >= n) return;
    const unsigned int* hg = histG + (size_t)rel * nblk * n + i;
    unsigned int lo = 0, hi = 0;
    int b = 0;
    for (; b + 8 <= nblk; b += 8) {
        unsigned v0 = hg[(size_t)(b + 0) * n];
        unsigned v1 = hg[(size_t)(b + 1) * n];
        unsigned v2 = hg[(size_t)(b + 2) * n];
        unsigned v3 = hg[(size_t)(b + 3) * n];
        unsigned v4 = hg[(size_t)(b + 4) * n];
        unsigned v5 = hg[(size_t)(b + 5) * n];
        unsigned v6 = hg[(size_t)(b + 6) * n];
        unsigned v7 = hg[(size_t)(b + 7) * n];
        lo += (v0 & 0xFFFFu) + (v1 & 0xFFFFu) + (v2 & 0xFFFFu) + (v3 & 0xFFFFu)
            + (v4 & 0xFFFFu) + (v5 & 0xFFFFu) + (v6 & 0xFFFFu) + (v7 & 0xFFFFu);
        hi += (v0 >> 16) + (v1 >> 16) + (v2 >> 16) + (v3 >> 16)
            + (v4 >> 16) + (v5 >> 16) + (v6 >> 16) + (v7 >> 16);
    }
    for (; b < nblk; ++b) {
        unsigned v = hg[(size_t)b * n];
        lo += v & 0xFFFFu;
        hi += v >> 16;
    }
    float so = rsqrtf((float)(lo > 1u ? lo : 1u));
    float si = rsqrtf((float)(hi > 1u ? hi : 1u));
    if (rel) { sOutU[i] = so; sInU[i] = si; degInU[i] = (int)hi; }
    else     { sOutS[i] = so; sInS[i] = si; degInS[i] = (int)hi; }
}

// ---------------------------------------------------------------- scan phase 1
__global__ __launch_bounds__(256) void scan_part_kernel(const int* __restrict__ degA,
                                                        const int* __restrict__ degB,
                                                        int n, int NB, int* __restrict__ bsum) {
    const int rel = blockIdx.y;
    const int* deg = rel ? degB : degA;
    int t = threadIdx.x;
    int base = blockIdx.x * SCHUNK + t * 8;
    int s = 0;
    if (base + 8 <= n) {
        int4 a = *(const int4*)(deg + base);
        int4 b = *(const int4*)(deg + base + 4);
        s = a.x + a.y + a.z + a.w + b.x + b.y + b.z + b.w;
    } else {
        for (int i = 0; i < 8; ++i)
            if (base + i < n) s += deg[base + i];
    }
    __shared__ int sm[256];
    sm[t] = s;
    __syncthreads();
    for (int off = 128; off > 0; off >>= 1) {
        if (t < off) sm[t] += sm[t + off];
        __syncthreads();
    }
    if (t == 0) bsum[rel * NB + blockIdx.x] = sm[0];
}

// ---------------------------------------------------------------- scan phase 2
__global__ void scan_mid_kernel(int* __restrict__ bsum, int NB,
                                int* __restrict__ rpA, int* __restrict__ rpB, int n) {
    int t = threadIdx.x;
    if (t >= 2) return;
    int* bs = bsum + t * NB;
    int run = 0;
    for (int i = 0; i < NB; ++i) {
        int v = bs[i];
        bs[i] = run;
        run += v;
    }
    int* rp = t ? rpB : rpA;
    rp[n] = run;
}

// ---------------------------------------------------------------- scan phase 3
__global__ __launch_bounds__(256) void scan_final_kernel(const int* __restrict__ degA,
                                                         const int* __restrict__ degB,
                                                         const int* __restrict__ bsum,
                                                         int n, int NB,
                                                         int* __restrict__ rpA,
                                                         int* __restrict__ rpB) {
    const int rel = blockIdx.y;
    const int* deg = rel ? degB : degA;
    int* rp = rel ? rpB : rpA;
    int t = threadIdx.x;
    int base = blockIdx.x * SCHUNK + t * 8;
    int v[8];
    if (base + 8 <= n) {
        int4 a = *(const int4*)(deg + base);
        int4 b = *(const int4*)(deg + base + 4);
        v[0] = a.x; v[1] = a.y; v[2] = a.z; v[3] = a.w;
        v[4] = b.x; v[5] = b.y; v[6] = b.z; v[7] = b.w;
    } else {
        for (int i = 0; i < 8; ++i) v[i] = (base + i < n) ? deg[base + i] : 0;
    }
    int s = 0;
    #pragma unroll
    for (int i = 0; i < 8; ++i) s += v[i];
    __shared__ int sm[256];
    sm[t] = s;
    __syncthreads();
    #pragma unroll
    for (int off = 1; off < 256; off <<= 1) {
        int y = (t >= off) ? sm[t - off] : 0;
        __syncthreads();
        sm[t] += y;
        __syncthreads();
    }
    int run = bsum[rel * NB + blockIdx.x] + sm[t] - s;
    #pragma unroll
    for (int i = 0; i < 8; ++i) {
        if (base + i < n) rp[base + i] = run;
        run += v[i];
    }
}

// ---------------------------------------------------------------- phase B2: per-block scatter offsets
// Unrolled x8 like totals.
__global__ void offsets_kernel(const unsigned int* __restrict__ histG,
                               const int* __restrict__ rpS, const int* __restrict__ rpU,
                               int n, int nblk, int* __restrict__ offsG) {
    const int rel = blockIdx.y;
    int i = blockIdx.x * 256 + threadIdx.x;
    if (i >= n) return;
    const unsigned int* hg = histG + (size_t)rel * nblk * n + i;
    int* og = offsG + (size_t)rel * nblk * n + i;
    int run = (rel ? rpU : rpS)[i];
    int b = 0;
    for (; b + 8 <= nblk; b += 8) {
        unsigned v0 = hg[(size_t)(b + 0) * n];
        unsigned v1 = hg[(size_t)(b + 1) * n];
        unsigned v2 = hg[(size_t)(b + 2) * n];
        unsigned v3 = hg[(size_t)(b + 3) * n];
        unsigned v4 = hg[(size_t)(b + 4) * n];
        unsigned v5 = hg[(size_t)(b + 5) * n];
        unsigned v6 = hg[(size_t)(b + 6) * n];
        unsigned v7 = hg[(size_t)(b + 7) * n];
        og[(size_t)(b + 0) * n] = run; run += (int)(v0 >> 16);
        og[(size_t)(b + 1) * n] = run; run += (int)(v1 >> 16);
        og[(size_t)(b + 2) * n] = run; run += (int)(v2 >> 16);
        og[(size_t)(b + 3) * n] = run; run += (int)(v3 >> 16);
        og[(size_t)(b + 4) * n] = run; run += (int)(v4 >> 16);
        og[(size_t)(b + 5) * n] = run; run += (int)(v5 >> 16);
        og[(size_t)(b + 6) * n] = run; run += (int)(v6 >> 16);
        og[(size_t)(b + 7) * n] = run; run += (int)(v7 >> 16);
    }
    for (; b < nblk; ++b) {
        unsigned v = hg[(size_t)b * n];
        og[(size_t)b * n] = run;
        run += (int)(v >> 16);
    }
}

// ---------------------------------------------------------------- phase C: CSR scatter, packed (u, w)
__global__ __launch_bounds__(256) void csr_scatter_kernel(
    const int* __restrict__ sS, const int* __restrict__ dS,
    const int* __restrict__ sU, const int* __restrict__ dU,
    int Es, int Eu, int n, int nblk, const int* __restrict__ offsG,
    const float* __restrict__ sOutS, const float* __restrict__ sOutU,
    int2* __restrict__ csrPS, int2* __restrict__ csrPU) {
    __shared__ int off[MAXN];
    const int rel = blockIdx.y;
    const int* src = rel ? sU : sS;
    const int* dst = rel ? dU : dS;
    const float* so = rel ? sOutU : sOutS;
    int2* csrP = rel ? csrPU : csrPS;
    int E = rel ? Eu : Es;
    int b = blockIdx.x;
    int chunk = (E + nblk - 1) / nblk;  // MUST match hist_kernel
    int beg = b * chunk;
    int end = min(E, beg + chunk);
    const int* og = offsG + ((size_t)rel * nblk + b) * n;
    for (int i = threadIdx.x; i < n; i += 256) off[i] = og[i];
    __syncthreads();
    for (int i = beg + threadIdx.x; i < end; i += 256) {
        int s = src[i];
        int pos = atomicAdd(&off[dst[i]], 1);
        csrP[pos] = make_int2(s, __float_as_int(so[s]));
    }
}

// ---------------------------------------------------------------- sliced pull aggregation (R8-proven)
// block = (chunk, rel, slice); slice = blockIdx.x & 7 pins slice -> XCD (2.56 MB/XCD L2).
// Wave: one node at a time; 8 subgroups x 8 lanes, each subgroup handles one edge
// per step, lane holds float4 (slice = 32 floats). 64-edge coalesced register batch;
// consume loop unrolled x4 so 4 independent 16B gathers are in flight per wave.
__global__ __launch_bounds__(256) void pull_slice_kernel(
    const float4* __restrict__ xin,      // [n][64] float4
    const int2* __restrict__ csrPS, const int2* __restrict__ csrPU,
    const int* __restrict__ rpS, const int* __restrict__ rpU,
    const float* __restrict__ sinS, const float* __restrict__ sinU,
    unsigned short* __restrict__ aggPk, int n) {
    int bid = blockIdx.x;
    int slice = bid & (NSLICE - 1);
    int rest = bid >> 3;
    int rel = rest & 1;
    int chunk = rest >> 1;
    const int2* csrP = rel ? csrPU : csrPS;
    const int* rp = rel ? rpU : rpS;
    const float* sinv = rel ? sinU : sinS;

    int wave = threadIdx.x >> 6;
    int lane = threadIdx.x & 63;
    int sub = lane >> 3;          // 0..7 edge slot
    int sl = lane & 7;            // float4 index within slice
    int fbase = slice * 8 + sl;   // float4 index within a 64-float4 row
    int kstepg = rel * 8 + slice;

    int start = chunk * NPB;
    int lim = min(n, start + NPB);
    for (int node = start + wave; node < lim; node += 4) {
        int beg = rp[node], end = rp[node + 1];
        float ax = 0.f, ay = 0.f, az = 0.f, aw = 0.f;
        for (int eb = beg; eb < end; eb += 64) {
            int cnt = end - eb;
            if (cnt > 64) cnt = 64;
            int myu = 0;
            float myw = 0.f;
            if (lane < cnt) {
                int2 p = csrP[eb + lane];
                myu = p.x;
                myw = __int_as_float(p.y);
            }
            int jmax = (cnt + 7) >> 3;
            int j = 0;
            for (; j + 4 <= jmax; j += 4) {
                int i0 = j * 8 + sub;
                int u0 = __shfl(myu, i0);
                int u1 = __shfl(myu, i0 + 8);
                int u2 = __shfl(myu, i0 + 16);
                int u3 = __shfl(myu, i0 + 24);
                float w0 = __shfl(myw, i0);
                float w1 = __shfl(myw, i0 + 8);
                float w2 = __shfl(myw, i0 + 16);
                float w3 = __shfl(myw, i0 + 24);
                float4 a0 = xin[(size_t)u0 * 64 + fbase];
                float4 a1 = xin[(size_t)u1 * 64 + fbase];
                float4 a2 = xin[(size_t)u2 * 64 + fbase];
                float4 a3 = xin[(size_t)u3 * 64 + fbase];
                ax += w0 * a0.x + w1 * a1.x + w2 * a2.x + w3 * a3.x;
                ay += w0 * a0.y + w1 * a1.y + w2 * a2.y + w3 * a3.y;
                az += w0 * a0.z + w1 * a1.z + w2 * a2.z + w3 * a3.z;
                aw += w0 * a0.w + w1 * a1.w + w2 * a2.w + w3 * a3.w;
            }
            for (; j < jmax; ++j) {
                int idx = j * 8 + sub;
                int u = __shfl(myu, idx);
                float w = __shfl(myw, idx);
                float4 a = xin[(size_t)u * 64 + fbase];
                ax += w * a.x; ay += w * a.y; az += w * a.z; aw += w * a.w;
            }
        }
        // reduce across the 8 subgroups (lane bits 3,4,5)
        ax += __shfl_xor(ax, 8);  ax += __shfl_xor(ax, 16); ax += __shfl_xor(ax, 32);
        ay += __shfl_xor(ay, 8);  ay += __shfl_xor(ay, 16); ay += __shfl_xor(ay, 32);
        az += __shfl_xor(az, 8);  az += __shfl_xor(az, 16); az += __shfl_xor(az, 32);
        aw += __shfl_xor(aw, 8);  aw += __shfl_xor(aw, 16); aw += __shfl_xor(aw, 32);
        if (sub == 0) {
            float si = sinv[node];
            float vx = si * ax, vy = si * ay, vz = si * az, vw = si * aw;
            ushort4 hi4 = make_ushort4(f2bf(vx), f2bf(vy), f2bf(vz), f2bf(vw));
            ushort4 lo4 = make_ushort4(f2bf(vx - bf2f(hi4.x)), f2bf(vy - bf2f(hi4.y)),
                                       f2bf(vz - bf2f(hi4.z)), f2bf(vw - bf2f(hi4.w)));
            // fragment-packed store: kstep = rel*8+slice
            size_t frag = ((size_t)(node >> 4) * 16 + kstepg) * 2;
            size_t addr = frag * 512 + ((node & 15) + (sl >> 1) * 16) * 8 + (sl & 1) * 4;
            *(ushort4*)&aggPk[addr] = hi4;
            *(ushort4*)&aggPk[addr + 512] = lo4;
        }
    }
}

// ---------------------------------------------------------------- split-bf16 MFMA GEMM, LDS-staged
// C[M x 256] = (Ahi+Alo)[M x 512] @ W (+bias)(+relu), hi*hi + lo*hi + hi*lo.
// BM=80 (5 mtiles) x full 256 cols; 512 threads / 8 waves, wave = 2 ntiles.
// Per k-step the block cooperatively stages A(10 frags) + B(32 frags) = 42KB
// into LDS ONCE, shared by all 8 waves (kills the 8x cross-wave A re-read
// from L2 that made the flat version ~450MB/GEMM).
template <int RELU>
__global__ __launch_bounds__(512) void gemm_mfma_kernel(
    const short8* __restrict__ Apk, const short8* __restrict__ Bpk,
    const float* __restrict__ bias, float* __restrict__ C, int M) {
    __shared__ short8 lds[42][64];   // 42 frags x 64 lanes x 16B = 42KB
    int tid = threadIdx.x;
    int lane = tid & 63;
    int wv = tid >> 6;     // 0..7
    int mt0 = blockIdx.x * 5;
    int m0 = blockIdx.x * 80;
    if (m0 >= M) return;
    int nt0 = wv * 2;
    int col0 = wv * 32;
    int frow = lane & 15;

    f32x4 acc[5][2];
    #pragma unroll
    for (int fr = 0; fr < 5; ++fr)
        #pragma unroll
        for (int fc = 0; fc < 2; ++fc)
            acc[fr][fc] = (f32x4){0.f, 0.f, 0.f, 0.f};

    for (int ks = 0; ks < 16; ++ks) {
        __syncthreads();
        // stage 2688 16B slots: A frags f=0..9 (fr=f>>1, pl=f&1), B frags f=10..41
        #pragma unroll
        for (int r = 0; r < 6; ++r) {
            int s = r * 512 + tid;
            if (s < 2688) {
                int f = s >> 6, l = s & 63;
                if (f < 10) {
                    int fr = f >> 1, pl = f & 1;
                    lds[f][l] = Apk[((size_t)(mt0 + fr) * 16 + ks) * 128 + pl * 64 + l];
                } else {
                    int q = f - 10;
                    int nt = q >> 1, pl = q & 1;
                    lds[f][l] = Bpk[((size_t)nt * 16 + ks) * 128 + pl * 64 + l];
                }
            }
        }
        __syncthreads();
        short8 bh[2], bl[2];
        #pragma unroll
        for (int fc = 0; fc < 2; ++fc) {
            bh[fc] = lds[10 + (nt0 + fc) * 2 + 0][lane];
            bl[fc] = lds[10 + (nt0 + fc) * 2 + 1][lane];
        }
        #pragma unroll
        for (int fr = 0; fr < 5; ++fr) {
            short8 ah = lds[fr * 2 + 0][lane];
            short8 al = lds[fr * 2 + 1][lane];
            #pragma unroll
            for (int fc = 0; fc < 2; ++fc) {
                acc[fr][fc] = __builtin_amdgcn_mfma_f32_16x16x32_bf16(ah, bh[fc], acc[fr][fc], 0, 0, 0);
                acc[fr][fc] = __builtin_amdgcn_mfma_f32_16x16x32_bf16(al, bh[fc], acc[fr][fc], 0, 0, 0);
                acc[fr][fc] = __builtin_amdgcn_mfma_f32_16x16x32_bf16(ah, bl[fc], acc[fr][fc], 0, 0, 0);
            }
        }
    }

    #pragma unroll
    for (int fr = 0; fr < 5; ++fr)
        #pragma unroll
        for (int fc = 0; fc < 2; ++fc) {
            int c = col0 + fc * 16 + frow;
            float bc = bias[c];
            int rb = m0 + fr * 16 + (lane >> 4) * 4;
            #pragma unroll
            for (int j = 0; j < 4; ++j) {
                int r = rb + j;
                if (r < M) {
                    float v = acc[fr][fc][j] + bc;
                    if (RELU) v = fmaxf(v, 0.f);
                    C[(size_t)r * 256 + c] = v;
                }
            }
        }
}

// ---------------------------------------------------------------- launch
extern "C" void kernel_launch(void* const* d_in, const int* in_sizes, int n_in,
                              void* d_out, int out_size, void* d_ws, size_t ws_size,
                              hipStream_t stream) {
    const float* x   = (const float*)d_in[0];
    const int* sS    = (const int*)d_in[1];
    const int* dS    = (const int*)d_in[2];
    const int* sU    = (const int*)d_in[3];
    const int* dU    = (const int*)d_in[4];
    const float* W1s = (const float*)d_in[5];
    const float* b1s = (const float*)d_in[6];
    const float* W1u = (const float*)d_in[7];
    const float* b1u = (const float*)d_in[8];
    const float* W2s = (const float*)d_in[9];
    const float* b2s = (const float*)d_in[10];
    const float* W2u = (const float*)d_in[11];
    const float* b2u = (const float*)d_in[12];
    float* out = (float*)d_out;

    const int n  = in_sizes[0] / 256;
    const int Es = in_sizes[1];
    const int Eu = in_sizes[3];
    const int NB = (n + SCHUNK - 1) / SCHUNK;
    const int gemmGrid = (n + 79) / 80;
    const size_t AGG_BYTES = (size_t)((n + 15) / 16 + 16) * 16 * 2 * 512 * 2;
    const size_t BPK_BYTES = (size_t)16 * 16 * 2 * 512 * 2;

    auto plan = [&](int nb) -> size_t {
        size_t t = 0;
        auto add = [&](size_t b) { t = (t + 255) & ~(size_t)255; t += b; };
        add((size_t)2 * nb * n * 4);            // histG
        add((size_t)2 * nb * n * 4);            // offsG
        add((size_t)(n + 1) * 4); add((size_t)(n + 1) * 4);
        add((size_t)n * 4); add((size_t)n * 4); add((size_t)n * 4); add((size_t)n * 4);
        add((size_t)n * 4); add((size_t)n * 4); // degIn
        add(256 * 4); add(256 * 4);
        add((size_t)2 * NB * 4);
        add((size_t)Es * 8); add((size_t)Eu * 8);
        add(2 * BPK_BYTES);
        add(AGG_BYTES);
        add((size_t)n * 256 * 4);               // h
        return t;
    };
    const int nblk = (plan(128) <= ws_size) ? 128 : 32;

    char* ws = (char*)d_ws;
    size_t off = 0;
    auto alloc = [&](size_t bytes) -> void* {
        off = (off + 255) & ~(size_t)255;
        void* p = ws + off;
        off += bytes;
        return p;
    };

    unsigned int* histG = (unsigned int*)alloc((size_t)2 * nblk * n * 4);
    int* offsG   = (int*)alloc((size_t)2 * nblk * n * 4);
    int* rpS     = (int*)alloc((size_t)(n + 1) * 4);
    int* rpU     = (int*)alloc((size_t)(n + 1) * 4);
    float* sOutS = (float*)alloc((size_t)n * 4);
    float* sInS  = (float*)alloc((size_t)n * 4);
    float* sOutU = (float*)alloc((size_t)n * 4);
    float* sInU  = (float*)alloc((size_t)n * 4);
    int* degInS  = (int*)alloc((size_t)n * 4);
    int* degInU  = (int*)alloc((size_t)n * 4);
    float* bsum1 = (float*)alloc(256 * 4);
    float* bsum2 = (float*)alloc(256 * 4);
    int* bsumBlk = (int*)alloc((size_t)2 * NB * 4);
    int2* csrPS  = (int2*)alloc((size_t)Es * 8);
    int2* csrPU  = (int2*)alloc((size_t)Eu * 8);
    unsigned short* Bpk1 = (unsigned short*)alloc(2 * BPK_BYTES);
    unsigned short* Bpk2 = Bpk1 + BPK_BYTES / 2;
    unsigned short* aggPk = (unsigned short*)alloc(AGG_BYTES);
    float* h     = (float*)alloc((size_t)n * 256 * 4);

    // ---- preprocessing (no global atomics)
    bias_sum_kernel<<<1, 256, 0, stream>>>(b1s, b1u, b2s, b2u, bsum1, bsum2);
    wprep_kernel<<<dim3(512, 2), 256, 0, stream>>>(W1s, W1u, W2s, W2u, Bpk1, Bpk2);
    dim3 hg(nblk, 2);
    hist_kernel<<<hg, 256, 0, stream>>>(sS, dS, sU, dU, Es, Eu, n, nblk, histG);
    dim3 tg((n + 255) / 256, 2);
    totals_kernel<<<tg, 256, 0, stream>>>(histG, n, nblk, sOutS, sInS, sOutU, sInU,
                                          degInS, degInU);
    dim3 sg(NB, 2);
    scan_part_kernel<<<sg, 256, 0, stream>>>(degInS, degInU, n, NB, bsumBlk);
    scan_mid_kernel<<<1, 64, 0, stream>>>(bsumBlk, NB, rpS, rpU, n);
    scan_final_kernel<<<sg, 256, 0, stream>>>(degInS, degInU, bsumBlk, n, NB, rpS, rpU);
    offsets_kernel<<<tg, 256, 0, stream>>>(histG, rpS, rpU, n, nblk, offsG);
    csr_scatter_kernel<<<hg, 256, 0, stream>>>(sS, dS, sU, dU, Es, Eu, n, nblk, offsG,
                                               sOutS, sOutU, csrPS, csrPU);

    // ---- layers
    int chunks = (n + NPB - 1) / NPB;
    int pullGrid = NSLICE * 2 * chunks;
    const float4* x4 = (const float4*)x;
    const float4* h4 = (const float4*)h;
    const short8* A8 = (const short8*)aggPk;
    const short8* B81 = (const short8*)Bpk1;
    const short8* B82 = (const short8*)Bpk2;

    pull_slice_kernel<<<pullGrid, 256, 0, stream>>>(x4, csrPS, csrPU, rpS, rpU,
                                                    sInS, sInU, aggPk, n);
    gemm_mfma_kernel<1><<<gemmGrid, 512, 0, stream>>>(A8, B81, bsum1, h, n);
    pull_slice_kernel<<<pullGrid, 256, 0, stream>>>(h4, csrPS, csrPU, rpS, rpU,
                                                    sInS, sInU, aggPk, n);
    gemm_mfma_kernel<0><<<gemmGrid, 512, 0, stream>>>(A8, B82, bsum2, out, n);
}